// Round 7
// baseline (1293.494 us; speedup 1.0000x reference)
//
#include <hip/hip_runtime.h>

#define D 128

typedef float f32x4 __attribute__((ext_vector_type(4)));
typedef short s16x8 __attribute__((ext_vector_type(8)));
typedef unsigned short u16x8 __attribute__((ext_vector_type(8)));

static __device__ __forceinline__ unsigned short f2bf(float f) {
    unsigned int u = __float_as_uint(f);
    unsigned int r = (u + 0x7FFFu + ((u >> 16) & 1u)) >> 16;  // RNE
    return (unsigned short)r;
}
static __device__ __forceinline__ float bf2f(unsigned int lo16) {
    return __uint_as_float(lo16 << 16);
}

// ===========================================================================
// ULTRA tier
// ===========================================================================

// hist (per-node, global atomics) + per-partition counts (p = d>>13,
// LDS-aggregated) + feature->bf16 + W->Wt bf16, fused
__global__ void k_prep(const int* __restrict__ dst, int* __restrict__ cnt,
                       int* __restrict__ pcnt, const float* __restrict__ feature,
                       unsigned short* __restrict__ fb, int E, int NF4,
                       const float* __restrict__ W,
                       unsigned short* __restrict__ wt) {
    __shared__ int lp[8];
    if (threadIdx.x < 8) lp[threadIdx.x] = 0;
    __syncthreads();
    int tid = blockIdx.x * blockDim.x + threadIdx.x;
    int stride = gridDim.x * blockDim.x;
    for (int base = tid * 4; base < E; base += stride * 4) {
        if (base + 4 <= E) {
            int4 d4 = *reinterpret_cast<const int4*>(dst + base);
            #pragma unroll
            for (int u = 0; u < 4; ++u) {
                int d = (&d4.x)[u];
                atomicAdd(&cnt[d], 1);
                atomicAdd(&lp[d >> 13], 1);
            }
        } else {
            for (int i = base; i < E; ++i) {
                int d = dst[i];
                atomicAdd(&cnt[d], 1);
                atomicAdd(&lp[d >> 13], 1);
            }
        }
    }
    const f32x4* f4 = reinterpret_cast<const f32x4*>(feature);
    ushort4* fb4 = reinterpret_cast<ushort4*>(fb);
    for (int i = tid; i < NF4; i += stride) {
        f32x4 v = f4[i];
        ushort4 o;
        o.x = f2bf(v[0]);
        o.y = f2bf(v[1]);
        o.z = f2bf(v[2]);
        o.w = f2bf(v[3]);
        fb4[i] = o;
    }
    for (int i = tid; i < D * D; i += stride) {
        int n = i >> 7, k = i & 127;
        wt[i] = f2bf(W[k * D + n]);
    }
    __syncthreads();
    if (threadIdx.x < 8 && lp[threadIdx.x])
        atomicAdd(&pcnt[threadIdx.x], lp[threadIdx.x]);
}

// Pass A: bucket edges into <=8 coarse dst-partitions (p = d>>13) as packed
// (dst16|src16) pairs. Ballot-ranked per wave: one global atomic per
// (wave, partition), no LDS, coalesced ~9-lane runs.
__global__ __launch_bounds__(256) void k_bucket8(
    const int* __restrict__ src, const int* __restrict__ dst,
    const int* __restrict__ pcnt, int* __restrict__ pcur,
    unsigned int* __restrict__ pairs, int E, int npart) {
    int pb[9];
    pb[0] = 0;
    #pragma unroll
    for (int p = 0; p < 8; ++p)
        pb[p + 1] = pb[p] + ((p < npart) ? pcnt[p] : 0);
    int tid = blockIdx.x * blockDim.x + threadIdx.x;
    int stride = gridDim.x * blockDim.x;
    int lane = threadIdx.x & 63;
    unsigned long long lmask = (1ull << lane) - 1ull;
    for (int e = tid; e - lane < E; e += stride) {  // keep wave intact
        bool valid = e < E;
        int d = valid ? dst[e] : 0;
        int s = valid ? src[e] : 0;
        int p = valid ? (d >> 13) : 255;
        unsigned pr = ((unsigned)d << 16) | (unsigned)s;
        for (int pi = 0; pi < npart; ++pi) {
            unsigned long long mask = __ballot(p == pi);
            if (!mask) continue;
            int cntp = __popcll(mask);
            int leader = (int)__builtin_ctzll(mask);
            int base = 0;
            if (lane == leader) base = atomicAdd(&pcur[pi], cntp);
            base = __shfl(base, leader);
            if (p == pi) {
                int rank = __popcll(mask & lmask);
                pairs[pb[pi] + base + rank] = pr;
            }
        }
    }
}

// Fused scan+aggregate: block owns 32 nodes [w0,w0+32). Streams its coarse
// partition's pair range (L2-resident), compacts matches to an LDS queue,
// drains matches as full-wave 256B gathers of fb[src] accumulated into LDS
// f32 via ds_add. Epilogue: /deg (deg0 -> copy fb), bf16 -> hb.
__global__ __launch_bounds__(256) void k_aggfuse(
    const unsigned short* __restrict__ fb, const unsigned int* __restrict__ pairs,
    const int* __restrict__ pcnt, const int* __restrict__ cnt,
    unsigned short* __restrict__ hb, int N, int npart) {
    __shared__ float agg[32][D];      // 16KB
    __shared__ unsigned int q[1024];  // 4KB
    __shared__ int qn;

    int tid = threadIdx.x;
    int w0 = blockIdx.x * 32;
    int mypart = w0 >> 13;
    int pb = 0;
    for (int p = 0; p < mypart; ++p) pb += pcnt[p];
    int pe = pb + pcnt[mypart];

    // zero accumulators: 4096 f32 / 256 threads = 16 each
    #pragma unroll
    for (int k = 0; k < 4; ++k)
        *reinterpret_cast<f32x4*>(&agg[0][0] + (k * 256 + tid) * 4) =
            (f32x4){0.f, 0.f, 0.f, 0.f};

    int wv = tid >> 6;
    int lane = tid & 63;

    for (int bstep = pb; bstep < pe; bstep += 1024) {
        if (tid == 0) qn = 0;
        __syncthreads();
        #pragma unroll
        for (int k = 0; k < 4; ++k) {
            int idx = bstep + k * 256 + tid;
            if (idx < pe) {
                unsigned pr = pairs[idx];
                unsigned dd = (pr >> 16) - (unsigned)w0;
                if (dd < 32u) {
                    int pos = atomicAdd(&qn, 1);
                    q[pos] = pr;
                }
            }
        }
        __syncthreads();
        int m = qn;
        for (int i = wv; i < m; i += 8) {  // 2 entries in flight per wave
            unsigned pr0 = q[i];
            int i1 = i + 4;
            bool has1 = i1 < m;
            unsigned pr1 = has1 ? q[i1] : pr0;
            int d0 = (int)(pr0 >> 16) - w0;
            int s0 = (int)(pr0 & 0xFFFFu);
            int d1 = (int)(pr1 >> 16) - w0;
            int s1 = (int)(pr1 & 0xFFFFu);
            unsigned v0 = *reinterpret_cast<const unsigned*>(
                fb + (size_t)s0 * D + lane * 2);
            unsigned v1 = *reinterpret_cast<const unsigned*>(
                fb + (size_t)s1 * D + lane * 2);
            atomicAdd(&agg[d0][lane * 2], bf2f(v0 & 0xFFFFu));
            atomicAdd(&agg[d0][lane * 2 + 1], bf2f(v0 >> 16));
            if (has1) {
                atomicAdd(&agg[d1][lane * 2], bf2f(v1 & 0xFFFFu));
                atomicAdd(&agg[d1][lane * 2 + 1], bf2f(v1 >> 16));
            }
        }
        __syncthreads();
    }

    // epilogue: 8 threads per row, 16 elems each
    int row = tid >> 3;
    int seg = tid & 7;
    int gnode = w0 + row;
    if (gnode < N) {
        int deg = cnt[gnode];
        unsigned short* op = hb + (size_t)gnode * D + seg * 16;
        if (deg == 0) {
            const unsigned short* ip = fb + (size_t)gnode * D + seg * 16;
            u16x8 a = *reinterpret_cast<const u16x8*>(ip);
            u16x8 bq = *reinterpret_cast<const u16x8*>(ip + 8);
            *reinterpret_cast<u16x8*>(op) = a;
            *reinterpret_cast<u16x8*>(op + 8) = bq;
        } else {
            float inv = 1.f / (float)deg;
            u16x8 o0, o1;
            #pragma unroll
            for (int j = 0; j < 8; ++j) {
                o0[j] = f2bf(agg[row][seg * 16 + j] * inv);
                o1[j] = f2bf(agg[row][seg * 16 + 8 + j] * inv);
            }
            *reinterpret_cast<u16x8*>(op) = o0;
            *reinterpret_cast<u16x8*>(op + 8) = o1;
        }
    }
}

// ===========================================================================
// Finalize GEMM: out = relu(h @ W + b). XOR-swizzled LDS, 16x16x32 MFMA.
// ===========================================================================
__global__ __launch_bounds__(256) void k_finalize_mfma(
    const unsigned short* __restrict__ hb, const unsigned short* __restrict__ Wt,
    const float* __restrict__ b, float* __restrict__ out, int N) {
    __shared__ char lds[65536];

    int t = threadIdx.x;
    int row0 = blockIdx.x * 128;

    #pragma unroll
    for (int i = 0; i < 8; ++i) {
        int chunk = i * 256 + t;
        int row = chunk >> 4;
        int c16 = chunk & 15;
        int ldsoff = row * 256 + ((c16 * 16) ^ ((row & 7) << 4));
        f32x4 v = {0.f, 0.f, 0.f, 0.f};
        int grow = row0 + row;
        if (grow < N)
            v = *reinterpret_cast<const f32x4*>(hb + (size_t)grow * D + c16 * 8);
        *reinterpret_cast<f32x4*>(&lds[ldsoff]) = v;
    }
    #pragma unroll
    for (int i = 0; i < 8; ++i) {
        int chunk = i * 256 + t;
        int row = chunk >> 4;
        int c16 = chunk & 15;
        int ldsoff = 32768 + row * 256 + ((c16 * 16) ^ ((row & 7) << 4));
        f32x4 v = *reinterpret_cast<const f32x4*>(Wt + (size_t)row * D + c16 * 8);
        *reinterpret_cast<f32x4*>(&lds[ldsoff]) = v;
    }
    __syncthreads();

    int wv = t >> 6;
    int l = t & 63;
    int l15 = l & 15;
    int lhi = l >> 4;

    f32x4 acc[2][8];
    #pragma unroll
    for (int m = 0; m < 2; ++m)
        #pragma unroll
        for (int n = 0; n < 8; ++n) acc[m][n] = (f32x4){0.f, 0.f, 0.f, 0.f};

    #pragma unroll
    for (int kk = 0; kk < 4; ++kk) {
        int kb = kk * 64 + lhi * 16;
        s16x8 af[2], bf[8];
        #pragma unroll
        for (int m = 0; m < 2; ++m) {
            int r = wv * 32 + m * 16 + l15;
            af[m] = *reinterpret_cast<const s16x8*>(
                &lds[r * 256 + (kb ^ ((r & 7) << 4))]);
        }
        #pragma unroll
        for (int n = 0; n < 8; ++n) {
            int r = n * 16 + l15;
            bf[n] = *reinterpret_cast<const s16x8*>(
                &lds[32768 + r * 256 + (kb ^ ((r & 7) << 4))]);
        }
        #pragma unroll
        for (int m = 0; m < 2; ++m)
            #pragma unroll
            for (int n = 0; n < 8; ++n)
                acc[m][n] = __builtin_amdgcn_mfma_f32_16x16x32_bf16(
                    af[m], bf[n], acc[m][n], 0, 0, 0);
    }

    #pragma unroll
    for (int n = 0; n < 8; ++n) {
        int col = n * 16 + l15;
        float bv = b[col];
        #pragma unroll
        for (int m = 0; m < 2; ++m) {
            int rbase = row0 + wv * 32 + m * 16 + lhi * 4;
            #pragma unroll
            for (int j = 0; j < 4; ++j) {
                int row = rbase + j;
                if (row < N)
                    out[(size_t)row * D + col] = fmaxf(acc[m][n][j] + bv, 0.f);
            }
        }
    }
}

// ===========================================================================
// Tier-2 kernels (fp32-feature gather, int srcs, unordered alloc)
// ===========================================================================
__global__ void k_hist(const int* __restrict__ dst, int* __restrict__ cnt,
                       int E) {
    int stride = gridDim.x * blockDim.x;
    for (int i = blockIdx.x * blockDim.x + threadIdx.x; i < E; i += stride)
        atomicAdd(&cnt[dst[i]], 1);
}

__global__ void k_alloc(const int* __restrict__ cnt, int* __restrict__ offset,
                        int* __restrict__ cursor, int* __restrict__ gtot,
                        int N, const float* __restrict__ W,
                        unsigned short* __restrict__ wt) {
    int i = blockIdx.x * blockDim.x + threadIdx.x;
    int lane = threadIdx.x & 63;
    if (W && i < D * D) {
        int n = i >> 7, k = i & 127;
        wt[i] = f2bf(W[k * D + n]);
    }
    int c = (i < N) ? cnt[i] : 0;
    int s = c;
    #pragma unroll
    for (int o = 1; o < 64; o <<= 1) {
        int t = __shfl_up(s, o);
        if (lane >= o) s += t;
    }
    int wavesum = __shfl(s, 63);
    int base = 0;
    if (lane == 0) base = atomicAdd(gtot, wavesum);
    base = __shfl(base, 0);
    if (i < N) {
        int off = base + s - c;
        offset[i] = off;
        cursor[i] = off;
    }
}

__global__ void k_fill(const int* __restrict__ src, const int* __restrict__ dst,
                       int* __restrict__ cursor, int* __restrict__ srcs,
                       int E) {
    int stride = gridDim.x * blockDim.x;
    for (int i = blockIdx.x * blockDim.x + threadIdx.x; i < E; i += stride) {
        int d = dst[i];
        int p = atomicAdd(&cursor[d], 1);
        srcs[p] = src[i];
    }
}

__global__ __launch_bounds__(256) void k_aggregate_bf16(
    const float* __restrict__ feature, const int* __restrict__ srcs,
    const int* __restrict__ offset, const int* __restrict__ cnt,
    unsigned short* __restrict__ hb, int N) {
    int w = (blockIdx.x * blockDim.x + threadIdx.x) >> 6;
    int lane = threadIdx.x & 63;
    if (w >= N) return;
    int sub = lane >> 5;
    int c0 = (lane & 31) * 4;
    int n = cnt[w];
    f32x4 acc = {0.f, 0.f, 0.f, 0.f};
    if (n == 0) {
        if (sub == 0)
            acc = *reinterpret_cast<const f32x4*>(feature + (size_t)w * D + c0);
    } else {
        int base = offset[w];
        int j = 0;
        for (; j + 4 <= n; j += 4) {
            int s0 = srcs[base + j + sub];
            int s1 = srcs[base + j + 2 + sub];
            f32x4 v0 = *reinterpret_cast<const f32x4*>(feature + (size_t)s0 * D + c0);
            f32x4 v1 = *reinterpret_cast<const f32x4*>(feature + (size_t)s1 * D + c0);
            acc += v0 + v1;
        }
        for (; j < n; j += 2) {
            if (j + sub < n) {
                int s0 = srcs[base + j + sub];
                f32x4 v0 = *reinterpret_cast<const f32x4*>(feature + (size_t)s0 * D + c0);
                acc += v0;
            }
        }
    }
    #pragma unroll
    for (int i = 0; i < 4; ++i) acc[i] += __shfl_xor(acc[i], 32);
    if (n > 1) {
        float r = 1.f / (float)n;
        #pragma unroll
        for (int i = 0; i < 4; ++i) acc[i] *= r;
    }
    if (sub == 0) {
        ushort4 o;
        o.x = f2bf(acc[0]);
        o.y = f2bf(acc[1]);
        o.z = f2bf(acc[2]);
        o.w = f2bf(acc[3]);
        *reinterpret_cast<ushort4*>(hb + (size_t)w * D + c0) = o;
    }
}

// ===========================================================================
// Tier-3/4 fallbacks
// ===========================================================================
__global__ __launch_bounds__(256) void k_aggregate_f32(
    const float* __restrict__ feature, const int* __restrict__ srcs,
    const int* __restrict__ offset, const int* __restrict__ cnt,
    float* __restrict__ h, int N) {
    int w = (blockIdx.x * blockDim.x + threadIdx.x) >> 6;
    int lane = threadIdx.x & 63;
    if (w >= N) return;
    int n = cnt[w];
    float2 acc = make_float2(0.f, 0.f);
    if (n == 0) {
        acc = *reinterpret_cast<const float2*>(feature + (size_t)w * D + lane * 2);
    } else {
        int base = offset[w];
        for (int j = 0; j < n; ++j) {
            int s0 = srcs[base + j];
            float2 v0 = *reinterpret_cast<const float2*>(feature + (size_t)s0 * D + lane * 2);
            acc.x += v0.x;
            acc.y += v0.y;
        }
        float r = 1.f / (float)n;
        acc.x *= r;
        acc.y *= r;
    }
    *reinterpret_cast<float2*>(h + (size_t)w * D + lane * 2) = acc;
}

__global__ void gcn_scatter(const float* __restrict__ feature,
                            const int* __restrict__ src,
                            const int* __restrict__ dst,
                            float* __restrict__ agg,
                            float* __restrict__ deg, int n_edges) {
    int gid = blockIdx.x * blockDim.x + threadIdx.x;
    int e = gid >> 6;
    int lane = gid & 63;
    if (e >= n_edges) return;
    int s = src[e];
    int d = dst[e];
    const float2 v =
        *reinterpret_cast<const float2*>(feature + (size_t)s * D + lane * 2);
    float* o = agg + (size_t)d * D + lane * 2;
    atomicAdd(o, v.x);
    atomicAdd(o + 1, v.y);
    if (lane == 0) atomicAdd(deg + d, 1.0f);
}

__global__ __launch_bounds__(256, 2) void gcn_finalize(
    float* __restrict__ inout, const float* __restrict__ feature,
    const float* __restrict__ W, const float* __restrict__ b,
    const float* __restrict__ deg, int n_nodes) {
    __shared__ float Ws[D * D];
    __shared__ float bs[D];
    __shared__ float hs[4][4][D];

    for (int i = threadIdx.x; i < (D * D) / 4; i += blockDim.x)
        reinterpret_cast<float4*>(Ws)[i] = reinterpret_cast<const float4*>(W)[i];
    if (threadIdx.x < D) bs[threadIdx.x] = b[threadIdx.x];
    __syncthreads();

    int wave = threadIdx.x >> 6;
    int lane = threadIdx.x & 63;
    int gwave = (blockIdx.x * blockDim.x + threadIdx.x) >> 6;
    int nwaves = (gridDim.x * blockDim.x) >> 6;
    int ngroups = (n_nodes + 3) / 4;

    for (int g = gwave; g < ngroups; g += nwaves) {
        int row0 = g * 4;
        #pragma unroll
        for (int r = 0; r < 4; ++r) {
            int row = row0 + r;
            if (row < n_nodes) {
                float2 h2;
                if (deg) {
                    float dg = deg[row];
                    if (dg > 0.f) {
                        float2 a = *reinterpret_cast<const float2*>(
                            inout + (size_t)row * D + lane * 2);
                        float rd = 1.f / dg;
                        h2.x = a.x * rd;
                        h2.y = a.y * rd;
                    } else {
                        h2 = *reinterpret_cast<const float2*>(
                            feature + (size_t)row * D + lane * 2);
                    }
                } else {
                    h2 = *reinterpret_cast<const float2*>(
                        inout + (size_t)row * D + lane * 2);
                }
                reinterpret_cast<float2*>(hs[wave][r])[lane] = h2;
            }
        }
        float acc2[4][2];
        #pragma unroll
        for (int r = 0; r < 4; ++r) {
            acc2[r][0] = bs[lane];
            acc2[r][1] = bs[lane + 64];
        }
        #pragma unroll 4
        for (int k = 0; k < D; ++k) {
            float w0 = Ws[k * D + lane];
            float w1 = Ws[k * D + lane + 64];
            #pragma unroll
            for (int r = 0; r < 4; ++r) {
                float hk = hs[wave][r][k];
                acc2[r][0] = fmaf(hk, w0, acc2[r][0]);
                acc2[r][1] = fmaf(hk, w1, acc2[r][1]);
            }
        }
        #pragma unroll
        for (int r = 0; r < 4; ++r) {
            int row = row0 + r;
            if (row < n_nodes) {
                inout[(size_t)row * D + lane] = fmaxf(acc2[r][0], 0.f);
                inout[(size_t)row * D + lane + 64] = fmaxf(acc2[r][1], 0.f);
            }
        }
    }
}

extern "C" void kernel_launch(void* const* d_in, const int* in_sizes, int n_in,
                              void* d_out, int out_size, void* d_ws,
                              size_t ws_size, hipStream_t stream) {
    const float* feature = (const float*)d_in[0];
    const float* W = (const float*)d_in[1];
    const float* b = (const float*)d_in[2];
    const int* src = (const int*)d_in[3];
    const int* dst = (const int*)d_in[4];
    int n_edges = in_sizes[3];
    int n_nodes = in_sizes[0] / D;

    float* out = (float*)d_out;
    int block = 256;
    int nrows_pad = ((n_nodes + 127) / 128) * 128;

    // ---- ULTRA layout (ints): cnt[N] | pcnt[8] | pcur[8] | pairs u32[E]
    //      then u16: fb[N*D] | hb[pad*D] | wt[D*D]
    size_t ints = (size_t)n_nodes + 16 + n_edges;
    size_t fb_off = (ints * sizeof(int) + 255) & ~(size_t)255;
    size_t hb_off = (fb_off + (size_t)n_nodes * D * 2 + 255) & ~(size_t)255;
    size_t wt_off = hb_off + (size_t)nrows_pad * D * 2;
    size_t need_ultra = wt_off + (size_t)D * D * 2;

    // ---- tier2 layout
    size_t csr_ints = (size_t)3 * n_nodes + 1 + n_edges;
    size_t csr_bytes = csr_ints * sizeof(int);
    size_t t2_hb_off = (csr_bytes + 255) & ~(size_t)255;
    size_t t2_wt_off = t2_hb_off + (size_t)nrows_pad * D * 2;
    size_t need_t2 = t2_wt_off + (size_t)D * D * 2;

    if (n_nodes < 65536 && ws_size >= need_ultra) {
        int* cnt = (int*)d_ws;
        int* pcnt = cnt + n_nodes;
        int* pcur = pcnt + 8;
        unsigned int* pairs = (unsigned int*)(pcur + 8);
        unsigned short* fb = (unsigned short*)((char*)d_ws + fb_off);
        unsigned short* hb = (unsigned short*)((char*)d_ws + hb_off);
        unsigned short* wt = (unsigned short*)((char*)d_ws + wt_off);

        int npart = (n_nodes + 8191) >> 13;  // <= 8 (n_nodes < 65536)

        hipMemsetAsync(cnt, 0, ((size_t)n_nodes + 16) * sizeof(int), stream);
        k_prep<<<2048, block, 0, stream>>>(dst, cnt, pcnt, feature, fb, n_edges,
                                           n_nodes * D / 4, W, wt);
        k_bucket8<<<2048, block, 0, stream>>>(src, dst, pcnt, pcur, pairs,
                                              n_edges, npart);
        k_aggfuse<<<(n_nodes + 31) / 32, block, 0, stream>>>(
            fb, pairs, pcnt, cnt, hb, n_nodes, npart);
        k_finalize_mfma<<<(n_nodes + 127) / 128, block, 0, stream>>>(
            hb, wt, b, out, n_nodes);
    } else if (ws_size >= need_t2) {
        int* cnt = (int*)d_ws;
        int* gtot = cnt + n_nodes;
        int* offset = gtot + 1;
        int* cursor = offset + n_nodes;
        int* srcs = cursor + n_nodes;
        unsigned short* hb = (unsigned short*)((char*)d_ws + t2_hb_off);
        unsigned short* wt = (unsigned short*)((char*)d_ws + t2_wt_off);

        hipMemsetAsync(cnt, 0, (size_t)(n_nodes + 1) * sizeof(int), stream);
        k_hist<<<2048, block, 0, stream>>>(dst, cnt, n_edges);
        k_alloc<<<(n_nodes + block - 1) / block, block, 0, stream>>>(
            cnt, offset, cursor, gtot, n_nodes, W, wt);
        k_fill<<<2048, block, 0, stream>>>(src, dst, cursor, srcs, n_edges);
        k_aggregate_bf16<<<((size_t)n_nodes * 64 + block - 1) / block, block, 0,
                           stream>>>(feature, srcs, offset, cnt, hb, n_nodes);
        k_finalize_mfma<<<(n_nodes + 127) / 128, block, 0, stream>>>(
            hb, wt, b, out, n_nodes);
    } else if (ws_size >= csr_bytes) {
        int* cnt = (int*)d_ws;
        int* gtot = cnt + n_nodes;
        int* offset = gtot + 1;
        int* cursor = offset + n_nodes;
        int* srcs = cursor + n_nodes;

        hipMemsetAsync(cnt, 0, (size_t)(n_nodes + 1) * sizeof(int), stream);
        k_hist<<<2048, block, 0, stream>>>(dst, cnt, n_edges);
        k_alloc<<<(n_nodes + block - 1) / block, block, 0, stream>>>(
            cnt, offset, cursor, gtot, n_nodes, nullptr, nullptr);
        k_fill<<<2048, block, 0, stream>>>(src, dst, cursor, srcs, n_edges);
        k_aggregate_f32<<<((size_t)n_nodes * 64 + block - 1) / block, block, 0,
                          stream>>>(feature, srcs, offset, cnt, out, n_nodes);
        gcn_finalize<<<512, block, 0, stream>>>(out, feature, W, b, nullptr,
                                                n_nodes);
    } else {
        float* deg = (float*)d_ws;
        hipMemsetAsync(out, 0, (size_t)out_size * sizeof(float), stream);
        hipMemsetAsync(deg, 0, (size_t)n_nodes * sizeof(float), stream);
        long long total_threads = (long long)n_edges * 64;
        int grid = (int)((total_threads + block - 1) / block);
        gcn_scatter<<<grid, block, 0, stream>>>(feature, src, dst, out, deg,
                                                n_edges);
        gcn_finalize<<<512, block, 0, stream>>>(out, feature, W, b, deg,
                                                n_nodes);
    }
}

// Round 8
// 380.869 us; speedup vs baseline: 3.3962x; 3.3962x over previous
//
#include <hip/hip_runtime.h>

#define D 128
#define FCH 512

typedef float f32x4 __attribute__((ext_vector_type(4)));
typedef float f32x8 __attribute__((ext_vector_type(8)));
typedef short s16x8 __attribute__((ext_vector_type(8)));
typedef unsigned short u16x8 __attribute__((ext_vector_type(8)));

static __device__ __forceinline__ unsigned short f2bf(float f) {
    unsigned int u = __float_as_uint(f);
    unsigned int r = (u + 0x7FFFu + ((u >> 16) & 1u)) >> 16;  // RNE
    return (unsigned short)r;
}
static __device__ __forceinline__ float bf2f(unsigned int lo16) {
    return __uint_as_float(lo16 << 16);
}
static __device__ __forceinline__ int cstart(int qi, int nchunk) {
    return (int)(((long long)qi * nchunk) >> 3);
}

// ===========================================================================
// PLAN-A tier: XCD-private 8-slice CSR
// ===========================================================================

// Chunk-claiming hist into per-XCD slice + fb/W bf16 conversion.
__global__ __launch_bounds__(256) void k_prep8(
    const int* __restrict__ dst, int* __restrict__ cnt8, int* __restrict__ qc,
    int* __restrict__ owner, const float* __restrict__ feature,
    unsigned short* __restrict__ fb, const float* __restrict__ W,
    unsigned short* __restrict__ wt, int E, int NF4, int Npad, int nchunk) {
    __shared__ int sc;
    unsigned xcc = ((unsigned)__builtin_amdgcn_s_getreg(63508)) & 7u;
    int* myslice = cnt8 + (int)xcc * Npad;
    for (int k = 0; k < 8; ++k) {
        int qi = (int)((xcc + (unsigned)k) & 7u);
        int q0 = cstart(qi, nchunk), q1 = cstart(qi + 1, nchunk);
        while (true) {
            __syncthreads();
            if (threadIdx.x == 0) sc = atomicAdd(&qc[qi], 1);
            __syncthreads();
            int idx = sc;
            if (idx >= q1 - q0) break;
            int c = q0 + idx;
            if (threadIdx.x == 0) owner[c] = (int)xcc;
            int e0 = c * FCH;
            int e1 = min(E, e0 + FCH);
            int e = e0 + (int)threadIdx.x * 2;
            if (e + 2 <= e1) {
                int2 d2 = *reinterpret_cast<const int2*>(dst + e);
                atomicAdd(&myslice[d2.x], 1);
                atomicAdd(&myslice[d2.y], 1);
            } else {
                for (int i = e; i < e1; ++i) atomicAdd(&myslice[dst[i]], 1);
            }
        }
    }
    // fb + wt conversion (grid-stride)
    int tid = blockIdx.x * blockDim.x + threadIdx.x;
    int stride = gridDim.x * blockDim.x;
    const f32x4* f4 = reinterpret_cast<const f32x4*>(feature);
    ushort4* fb4 = reinterpret_cast<ushort4*>(fb);
    for (int i = tid; i < NF4; i += stride) {
        f32x4 v = f4[i];
        ushort4 o;
        o.x = f2bf(v[0]);
        o.y = f2bf(v[1]);
        o.z = f2bf(v[2]);
        o.w = f2bf(v[3]);
        fb4[i] = o;
    }
    for (int i = tid; i < D * D; i += stride) {
        int n = i >> 7, k = i & 127;
        wt[i] = f2bf(W[k * D + n]);
    }
}

// Per-slice unordered allocation: cur8[i] = within-slice base for node,
// gtot8[x] accumulates slice size. Npad % 64 == 0 so waves never straddle x.
__global__ __launch_bounds__(256) void k_alloc8(const int* __restrict__ cnt8,
                                                int* __restrict__ cur8,
                                                int* __restrict__ gtot8,
                                                int total, int Npad) {
    int i = blockIdx.x * blockDim.x + threadIdx.x;
    if (i >= total) return;
    int lane = threadIdx.x & 63;
    int x = i / Npad;
    int c = cnt8[i];
    int s = c;
    #pragma unroll
    for (int o = 1; o < 64; o <<= 1) {
        int t = __shfl_up(s, o);
        if (lane >= o) s += t;
    }
    int wavesum = __shfl(s, 63);
    int base = 0;
    if (lane == 0) base = atomicAdd(&gtot8[x], wavesum);
    base = __shfl(base, 0);
    cur8[i] = base + s - c;
}

// Replay chunk claims; scatter u16 src into slice owner[c]'s region.
__global__ __launch_bounds__(256) void k_fill8(
    const int* __restrict__ src, const int* __restrict__ dst,
    const int* __restrict__ gtot8, int* __restrict__ qc,
    const int* __restrict__ owner, int* __restrict__ cur8,
    unsigned short* __restrict__ srcs, int E, int Npad, int nchunk) {
    __shared__ int sc;
    unsigned xcc = ((unsigned)__builtin_amdgcn_s_getreg(63508)) & 7u;
    int base8[8];
    {
        int run = 0;
        #pragma unroll
        for (int x = 0; x < 8; ++x) {
            base8[x] = run;
            run += gtot8[x];
        }
    }
    for (int k = 0; k < 8; ++k) {
        int qi = (int)((xcc + (unsigned)k) & 7u);
        int q0 = cstart(qi, nchunk), q1 = cstart(qi + 1, nchunk);
        while (true) {
            __syncthreads();
            if (threadIdx.x == 0) sc = atomicAdd(&qc[qi], 1);
            __syncthreads();
            int idx = sc;
            if (idx >= q1 - q0) break;
            int c = q0 + idx;
            int ow = owner[c];
            int* slice = cur8 + ow * Npad;
            int sbase = base8[ow];
            int e0 = c * FCH;
            int e1 = min(E, e0 + FCH);
            int e = e0 + (int)threadIdx.x * 2;
            if (e + 2 <= e1) {
                int2 d2 = *reinterpret_cast<const int2*>(dst + e);
                int2 s2 = *reinterpret_cast<const int2*>(src + e);
                int p0 = atomicAdd(&slice[d2.x], 1);
                int p1 = atomicAdd(&slice[d2.y], 1);
                srcs[sbase + p0] = (unsigned short)s2.x;
                srcs[sbase + p1] = (unsigned short)s2.y;
            } else {
                for (int i = e; i < e1; ++i) {
                    int p = atomicAdd(&slice[dst[i]], 1);
                    srcs[sbase + p] = (unsigned short)src[i];
                }
            }
        }
    }
}

// One wave per node: walk 8 sub-lists flattened, 4 gathers in flight.
// start_rel = cur8_final - cnt8 (fill advanced cur8 by exactly cnt8).
__global__ __launch_bounds__(256) void k_agg8(
    const unsigned short* __restrict__ fb, const unsigned short* __restrict__ srcs,
    const int* __restrict__ cnt8, const int* __restrict__ cur8,
    const int* __restrict__ gtot8, unsigned short* __restrict__ hb, int N,
    int Npad) {
    int w = (blockIdx.x * blockDim.x + threadIdx.x) >> 6;
    int lane = threadIdx.x & 63;
    if (w >= N) return;
    int sub = lane >> 4;
    int l15 = lane & 15;

    int pfx[9];
    int start8[8];
    {
        int run = 0, gbase = 0;
        #pragma unroll
        for (int x = 0; x < 8; ++x) {
            int n = cnt8[x * Npad + w];
            int endrel = cur8[x * Npad + w];
            start8[x] = gbase + endrel - n;
            pfx[x] = run;
            run += n;
            gbase += gtot8[x];
        }
        pfx[8] = run;
    }
    int deg = pfx[8];

    if (deg == 0) {
        if (sub == 0) {
            u16x8 v = *reinterpret_cast<const u16x8*>(fb + (size_t)w * D + l15 * 8);
            *reinterpret_cast<u16x8*>(hb + (size_t)w * D + l15 * 8) = v;
        }
        return;
    }

    f32x8 acc = {0.f, 0.f, 0.f, 0.f, 0.f, 0.f, 0.f, 0.f};
    for (int i0 = 0; i0 < deg; i0 += 4) {
        int i = i0 + sub;
        if (i < deg) {
            int x = 0;
            #pragma unroll
            for (int k = 1; k < 8; ++k) x += (i >= pfx[k]);
            int sid = srcs[start8[x] + (i - pfx[x])];
            u16x8 v = *reinterpret_cast<const u16x8*>(fb + (size_t)sid * D + l15 * 8);
            #pragma unroll
            for (int j = 0; j < 8; ++j)
                acc[j] += bf2f((unsigned int)(unsigned short)v[j]);
        }
    }
    #pragma unroll
    for (int j = 0; j < 8; ++j) acc[j] += __shfl_xor(acc[j], 16);
    #pragma unroll
    for (int j = 0; j < 8; ++j) acc[j] += __shfl_xor(acc[j], 32);
    if (sub == 0) {
        float inv = 1.f / (float)deg;
        u16x8 o;
        #pragma unroll
        for (int j = 0; j < 8; ++j) o[j] = f2bf(acc[j] * inv);
        *reinterpret_cast<u16x8*>(hb + (size_t)w * D + l15 * 8) = o;
    }
}

// ===========================================================================
// Finalize GEMM: out = relu(h @ W + b). XOR-swizzled LDS, 16x16x32 MFMA.
// ===========================================================================
__global__ __launch_bounds__(256) void k_finalize_mfma(
    const unsigned short* __restrict__ hb, const unsigned short* __restrict__ Wt,
    const float* __restrict__ b, float* __restrict__ out, int N) {
    __shared__ char lds[65536];

    int t = threadIdx.x;
    int row0 = blockIdx.x * 128;

    #pragma unroll
    for (int i = 0; i < 8; ++i) {
        int chunk = i * 256 + t;
        int row = chunk >> 4;
        int c16 = chunk & 15;
        int ldsoff = row * 256 + ((c16 * 16) ^ ((row & 7) << 4));
        f32x4 v = {0.f, 0.f, 0.f, 0.f};
        int grow = row0 + row;
        if (grow < N)
            v = *reinterpret_cast<const f32x4*>(hb + (size_t)grow * D + c16 * 8);
        *reinterpret_cast<f32x4*>(&lds[ldsoff]) = v;
    }
    #pragma unroll
    for (int i = 0; i < 8; ++i) {
        int chunk = i * 256 + t;
        int row = chunk >> 4;
        int c16 = chunk & 15;
        int ldsoff = 32768 + row * 256 + ((c16 * 16) ^ ((row & 7) << 4));
        f32x4 v = *reinterpret_cast<const f32x4*>(Wt + (size_t)row * D + c16 * 8);
        *reinterpret_cast<f32x4*>(&lds[ldsoff]) = v;
    }
    __syncthreads();

    int wv = t >> 6;
    int l = t & 63;
    int l15 = l & 15;
    int lhi = l >> 4;

    f32x4 acc[2][8];
    #pragma unroll
    for (int m = 0; m < 2; ++m)
        #pragma unroll
        for (int n = 0; n < 8; ++n) acc[m][n] = (f32x4){0.f, 0.f, 0.f, 0.f};

    #pragma unroll
    for (int kk = 0; kk < 4; ++kk) {
        int kb = kk * 64 + lhi * 16;
        s16x8 af[2], bf[8];
        #pragma unroll
        for (int m = 0; m < 2; ++m) {
            int r = wv * 32 + m * 16 + l15;
            af[m] = *reinterpret_cast<const s16x8*>(
                &lds[r * 256 + (kb ^ ((r & 7) << 4))]);
        }
        #pragma unroll
        for (int n = 0; n < 8; ++n) {
            int r = n * 16 + l15;
            bf[n] = *reinterpret_cast<const s16x8*>(
                &lds[32768 + r * 256 + (kb ^ ((r & 7) << 4))]);
        }
        #pragma unroll
        for (int m = 0; m < 2; ++m)
            #pragma unroll
            for (int n = 0; n < 8; ++n)
                acc[m][n] = __builtin_amdgcn_mfma_f32_16x16x32_bf16(
                    af[m], bf[n], acc[m][n], 0, 0, 0);
    }

    #pragma unroll
    for (int n = 0; n < 8; ++n) {
        int col = n * 16 + l15;
        float bv = b[col];
        #pragma unroll
        for (int m = 0; m < 2; ++m) {
            int rbase = row0 + wv * 32 + m * 16 + lhi * 4;
            #pragma unroll
            for (int j = 0; j < 4; ++j) {
                int row = rbase + j;
                if (row < N)
                    out[(size_t)row * D + col] = fmaxf(acc[m][n][j] + bv, 0.f);
            }
        }
    }
}

// ===========================================================================
// Tier-1.5: round-4 path (global CSR, u16 srcs)
// ===========================================================================
__global__ void k_prep4(const int* __restrict__ dst, int* __restrict__ cnt,
                        const float* __restrict__ feature,
                        unsigned short* __restrict__ fb, int E, int NF4,
                        const float* __restrict__ W,
                        unsigned short* __restrict__ wt) {
    int tid = blockIdx.x * blockDim.x + threadIdx.x;
    int stride = gridDim.x * blockDim.x;
    for (int base = tid * 4; base < E; base += stride * 4) {
        if (base + 4 <= E) {
            int4 d4 = *reinterpret_cast<const int4*>(dst + base);
            atomicAdd(&cnt[d4.x], 1);
            atomicAdd(&cnt[d4.y], 1);
            atomicAdd(&cnt[d4.z], 1);
            atomicAdd(&cnt[d4.w], 1);
        } else {
            for (int i = base; i < E; ++i) atomicAdd(&cnt[dst[i]], 1);
        }
    }
    const f32x4* f4 = reinterpret_cast<const f32x4*>(feature);
    ushort4* fb4 = reinterpret_cast<ushort4*>(fb);
    for (int i = tid; i < NF4; i += stride) {
        f32x4 v = f4[i];
        ushort4 o;
        o.x = f2bf(v[0]);
        o.y = f2bf(v[1]);
        o.z = f2bf(v[2]);
        o.w = f2bf(v[3]);
        fb4[i] = o;
    }
    for (int i = tid; i < D * D; i += stride) {
        int n = i >> 7, k = i & 127;
        wt[i] = f2bf(W[k * D + n]);
    }
}

__global__ void k_alloc(const int* __restrict__ cnt, int* __restrict__ offset,
                        int* __restrict__ cursor, int* __restrict__ gtot,
                        int N) {
    int i = blockIdx.x * blockDim.x + threadIdx.x;
    int lane = threadIdx.x & 63;
    int c = (i < N) ? cnt[i] : 0;
    int s = c;
    #pragma unroll
    for (int o = 1; o < 64; o <<= 1) {
        int t = __shfl_up(s, o);
        if (lane >= o) s += t;
    }
    int wavesum = __shfl(s, 63);
    int base = 0;
    if (lane == 0) base = atomicAdd(gtot, wavesum);
    base = __shfl(base, 0);
    if (i < N) {
        int off = base + s - c;
        offset[i] = off;
        cursor[i] = off;
    }
}

__global__ void k_fill_u16(const int* __restrict__ src,
                           const int* __restrict__ dst,
                           int* __restrict__ cursor,
                           unsigned short* __restrict__ srcs, int E) {
    int t = blockIdx.x * blockDim.x + threadIdx.x;
    int base = t * 4;
    if (base >= E) return;
    if (base + 4 <= E) {
        int4 d4 = *reinterpret_cast<const int4*>(dst + base);
        int4 s4 = *reinterpret_cast<const int4*>(src + base);
        int p0 = atomicAdd(&cursor[d4.x], 1);
        int p1 = atomicAdd(&cursor[d4.y], 1);
        int p2 = atomicAdd(&cursor[d4.z], 1);
        int p3 = atomicAdd(&cursor[d4.w], 1);
        srcs[p0] = (unsigned short)s4.x;
        srcs[p1] = (unsigned short)s4.y;
        srcs[p2] = (unsigned short)s4.z;
        srcs[p3] = (unsigned short)s4.w;
    } else {
        for (int i = base; i < E; ++i) {
            int p = atomicAdd(&cursor[dst[i]], 1);
            srcs[p] = (unsigned short)src[i];
        }
    }
}

__global__ __launch_bounds__(256) void k_aggregate_u16(
    const unsigned short* __restrict__ fb,
    const unsigned short* __restrict__ srcs, const int* __restrict__ offset,
    const int* __restrict__ cnt, unsigned short* __restrict__ hb, int N) {
    int w = (blockIdx.x * blockDim.x + threadIdx.x) >> 6;
    int lane = threadIdx.x & 63;
    if (w >= N) return;
    int sub = lane >> 4;
    int l15 = lane & 15;
    int n = cnt[w];
    if (n == 0) {
        if (sub == 0) {
            u16x8 v = *reinterpret_cast<const u16x8*>(fb + (size_t)w * D + l15 * 8);
            *reinterpret_cast<u16x8*>(hb + (size_t)w * D + l15 * 8) = v;
        }
        return;
    }
    int base = offset[w];
    f32x8 acc = {0.f, 0.f, 0.f, 0.f, 0.f, 0.f, 0.f, 0.f};
    int j = 0;
    for (; j + 8 <= n; j += 8) {
        int s0 = srcs[base + j + sub];
        int s1 = srcs[base + j + 4 + sub];
        u16x8 v0 = *reinterpret_cast<const u16x8*>(fb + (size_t)s0 * D + l15 * 8);
        u16x8 v1 = *reinterpret_cast<const u16x8*>(fb + (size_t)s1 * D + l15 * 8);
        #pragma unroll
        for (int q = 0; q < 8; ++q) acc[q] += bf2f((unsigned int)(unsigned short)v0[q]);
        #pragma unroll
        for (int q = 0; q < 8; ++q) acc[q] += bf2f((unsigned int)(unsigned short)v1[q]);
    }
    for (; j < n; j += 4) {
        if (j + sub < n) {
            int s0 = srcs[base + j + sub];
            u16x8 v0 = *reinterpret_cast<const u16x8*>(fb + (size_t)s0 * D + l15 * 8);
            #pragma unroll
            for (int q = 0; q < 8; ++q) acc[q] += bf2f((unsigned int)(unsigned short)v0[q]);
        }
    }
    #pragma unroll
    for (int q = 0; q < 8; ++q) acc[q] += __shfl_xor(acc[q], 16);
    #pragma unroll
    for (int q = 0; q < 8; ++q) acc[q] += __shfl_xor(acc[q], 32);
    if (sub == 0) {
        float r = 1.f / (float)n;
        u16x8 o;
        #pragma unroll
        for (int q = 0; q < 8; ++q) o[q] = f2bf(acc[q] * r);
        *reinterpret_cast<u16x8*>(hb + (size_t)w * D + l15 * 8) = o;
    }
}

// ===========================================================================
// Tier-3/4 fallbacks
// ===========================================================================
__global__ void gcn_scatter(const float* __restrict__ feature,
                            const int* __restrict__ src,
                            const int* __restrict__ dst,
                            float* __restrict__ agg,
                            float* __restrict__ deg, int n_edges) {
    int gid = blockIdx.x * blockDim.x + threadIdx.x;
    int e = gid >> 6;
    int lane = gid & 63;
    if (e >= n_edges) return;
    int s = src[e];
    int d = dst[e];
    const float2 v =
        *reinterpret_cast<const float2*>(feature + (size_t)s * D + lane * 2);
    float* o = agg + (size_t)d * D + lane * 2;
    atomicAdd(o, v.x);
    atomicAdd(o + 1, v.y);
    if (lane == 0) atomicAdd(deg + d, 1.0f);
}

__global__ __launch_bounds__(256, 2) void gcn_finalize(
    float* __restrict__ inout, const float* __restrict__ feature,
    const float* __restrict__ W, const float* __restrict__ b,
    const float* __restrict__ deg, int n_nodes) {
    __shared__ float Ws[D * D];
    __shared__ float bs[D];
    __shared__ float hs[4][4][D];

    for (int i = threadIdx.x; i < (D * D) / 4; i += blockDim.x)
        reinterpret_cast<float4*>(Ws)[i] = reinterpret_cast<const float4*>(W)[i];
    if (threadIdx.x < D) bs[threadIdx.x] = b[threadIdx.x];
    __syncthreads();

    int wave = threadIdx.x >> 6;
    int lane = threadIdx.x & 63;
    int gwave = (blockIdx.x * blockDim.x + threadIdx.x) >> 6;
    int nwaves = (gridDim.x * blockDim.x) >> 6;
    int ngroups = (n_nodes + 3) / 4;

    for (int g = gwave; g < ngroups; g += nwaves) {
        int row0 = g * 4;
        #pragma unroll
        for (int r = 0; r < 4; ++r) {
            int row = row0 + r;
            if (row < n_nodes) {
                float2 h2;
                float dg = deg[row];
                if (dg > 0.f) {
                    float2 a = *reinterpret_cast<const float2*>(
                        inout + (size_t)row * D + lane * 2);
                    float rd = 1.f / dg;
                    h2.x = a.x * rd;
                    h2.y = a.y * rd;
                } else {
                    h2 = *reinterpret_cast<const float2*>(
                        feature + (size_t)row * D + lane * 2);
                }
                reinterpret_cast<float2*>(hs[wave][r])[lane] = h2;
            }
        }
        float acc2[4][2];
        #pragma unroll
        for (int r = 0; r < 4; ++r) {
            acc2[r][0] = bs[lane];
            acc2[r][1] = bs[lane + 64];
        }
        #pragma unroll 4
        for (int k = 0; k < D; ++k) {
            float w0 = Ws[k * D + lane];
            float w1 = Ws[k * D + lane + 64];
            #pragma unroll
            for (int r = 0; r < 4; ++r) {
                float hk = hs[wave][r][k];
                acc2[r][0] = fmaf(hk, w0, acc2[r][0]);
                acc2[r][1] = fmaf(hk, w1, acc2[r][1]);
            }
        }
        #pragma unroll
        for (int r = 0; r < 4; ++r) {
            int row = row0 + r;
            if (row < n_nodes) {
                inout[(size_t)row * D + lane] = fmaxf(acc2[r][0], 0.f);
                inout[(size_t)row * D + lane + 64] = fmaxf(acc2[r][1], 0.f);
            }
        }
    }
}

extern "C" void kernel_launch(void* const* d_in, const int* in_sizes, int n_in,
                              void* d_out, int out_size, void* d_ws,
                              size_t ws_size, hipStream_t stream) {
    const float* feature = (const float*)d_in[0];
    const float* W = (const float*)d_in[1];
    const float* b = (const float*)d_in[2];
    const int* src = (const int*)d_in[3];
    const int* dst = (const int*)d_in[4];
    int n_edges = in_sizes[3];
    int n_nodes = in_sizes[0] / D;

    float* out = (float*)d_out;
    int block = 256;
    int nrows_pad = ((n_nodes + 127) / 128) * 128;
    int Npad = (n_nodes + 63) & ~63;
    int nchunk = (n_edges + FCH - 1) / FCH;

    // ---- PLAN-A layout (ints): cnt8[8*Npad] | gtot8[8] | qc1[8] | qc2[8] |
    //      owner[nchunk_pad] | cur8[8*Npad]
    //      then u16: srcs[E] | fb[N*D] | hb[pad*D] | wt[D*D]
    int nchunk_pad = (nchunk + 63) & ~63;
    size_t intsA = (size_t)16 * Npad + 24 + nchunk_pad;
    size_t a_srcs_off = (intsA * sizeof(int) + 255) & ~(size_t)255;
    size_t a_fb_off = (a_srcs_off + (size_t)n_edges * 2 + 255) & ~(size_t)255;
    size_t a_hb_off = (a_fb_off + (size_t)n_nodes * D * 2 + 255) & ~(size_t)255;
    size_t a_wt_off = a_hb_off + (size_t)nrows_pad * D * 2;
    size_t need_a = a_wt_off + (size_t)D * D * 2;

    // ---- tier-1.5 layout (round-4): cnt[N] gtot[1] offset[N] cursor[N] |
    //      srcs u16[E] | fb | hb | wt
    size_t intsB = (size_t)3 * n_nodes + 1;
    size_t b_srcs_off = intsB * sizeof(int);
    size_t b_fb_off = (b_srcs_off + (size_t)n_edges * 2 + 255) & ~(size_t)255;
    size_t b_hb_off = (b_fb_off + (size_t)n_nodes * D * 2 + 255) & ~(size_t)255;
    size_t b_wt_off = b_hb_off + (size_t)nrows_pad * D * 2;
    size_t need_b = b_wt_off + (size_t)D * D * 2;

    if (n_nodes < 65536 && ws_size >= need_a) {
        int* cnt8 = (int*)d_ws;
        int* gtot8 = cnt8 + (size_t)8 * Npad;
        int* qc1 = gtot8 + 8;
        int* qc2 = qc1 + 8;
        int* owner = qc2 + 8;
        int* cur8 = owner + nchunk_pad;
        unsigned short* srcs = (unsigned short*)((char*)d_ws + a_srcs_off);
        unsigned short* fb = (unsigned short*)((char*)d_ws + a_fb_off);
        unsigned short* hb = (unsigned short*)((char*)d_ws + a_hb_off);
        unsigned short* wt = (unsigned short*)((char*)d_ws + a_wt_off);

        // zero cnt8 + gtot8 + qc1 + qc2 (contiguous)
        hipMemsetAsync(cnt8, 0, ((size_t)8 * Npad + 24) * sizeof(int), stream);
        k_prep8<<<1024, block, 0, stream>>>(dst, cnt8, qc1, owner, feature, fb,
                                            W, wt, n_edges, n_nodes * D / 4,
                                            Npad, nchunk);
        k_alloc8<<<(8 * Npad + block - 1) / block, block, 0, stream>>>(
            cnt8, cur8, gtot8, 8 * Npad, Npad);
        k_fill8<<<1024, block, 0, stream>>>(src, dst, gtot8, qc2, owner, cur8,
                                            srcs, n_edges, Npad, nchunk);
        k_agg8<<<((size_t)n_nodes * 64 + block - 1) / block, block, 0, stream>>>(
            fb, srcs, cnt8, cur8, gtot8, hb, n_nodes, Npad);
        k_finalize_mfma<<<(n_nodes + 127) / 128, block, 0, stream>>>(
            hb, wt, b, out, n_nodes);
    } else if (n_nodes < 65536 && ws_size >= need_b) {
        int* cnt = (int*)d_ws;
        int* gtot = cnt + n_nodes;
        int* offset = gtot + 1;
        int* cursor = offset + n_nodes;
        unsigned short* srcs = (unsigned short*)((char*)d_ws + b_srcs_off);
        unsigned short* fb = (unsigned short*)((char*)d_ws + b_fb_off);
        unsigned short* hb = (unsigned short*)((char*)d_ws + b_hb_off);
        unsigned short* wt = (unsigned short*)((char*)d_ws + b_wt_off);

        hipMemsetAsync(cnt, 0, (size_t)(n_nodes + 1) * sizeof(int), stream);
        k_prep4<<<2048, block, 0, stream>>>(dst, cnt, feature, fb, n_edges,
                                            n_nodes * D / 4, W, wt);
        k_alloc<<<(n_nodes + block - 1) / block, block, 0, stream>>>(
            cnt, offset, cursor, gtot, n_nodes);
        k_fill_u16<<<(n_edges / 4 + block) / block, block, 0, stream>>>(
            src, dst, cursor, srcs, n_edges);
        k_aggregate_u16<<<((size_t)n_nodes * 64 + block - 1) / block, block, 0,
                          stream>>>(fb, srcs, offset, cnt, hb, n_nodes);
        k_finalize_mfma<<<(n_nodes + 127) / 128, block, 0, stream>>>(
            hb, wt, b, out, n_nodes);
    } else {
        float* deg = (float*)d_ws;
        hipMemsetAsync(out, 0, (size_t)out_size * sizeof(float), stream);
        hipMemsetAsync(deg, 0, (size_t)n_nodes * sizeof(float), stream);
        long long total_threads = (long long)n_edges * 64;
        int grid = (int)((total_threads + block - 1) / block);
        gcn_scatter<<<grid, block, 0, stream>>>(feature, src, dst, out, deg,
                                                n_edges);
        gcn_finalize<<<512, block, 0, stream>>>(out, feature, W, b, deg,
                                                n_nodes);
    }
}

// Round 9
// 105.645 us; speedup vs baseline: 12.2438x; 3.6052x over previous
//
#include <hip/hip_runtime.h>

#define D 128

typedef float f32x4 __attribute__((ext_vector_type(4)));
typedef float f32x8 __attribute__((ext_vector_type(8)));
typedef short s16x8 __attribute__((ext_vector_type(8)));
typedef unsigned short u16x8 __attribute__((ext_vector_type(8)));

static __device__ __forceinline__ unsigned short f2bf(float f) {
    unsigned int u = __float_as_uint(f);
    unsigned int r = (u + 0x7FFFu + ((u >> 16) & 1u)) >> 16;  // RNE
    return (unsigned short)r;
}
static __device__ __forceinline__ float bf2f(unsigned int lo16) {
    return __uint_as_float(lo16 << 16);
}

// ===========================================================================
// PRIMARY tier (round-4 skeleton + rank trick)
// ===========================================================================

// hist whose atomicAdd return value IS the edge's within-node rank (stored),
// + feature->bf16 + W->Wt bf16, fused.
__global__ void k_prep_rank(const int* __restrict__ dst, int* __restrict__ cnt,
                            int* __restrict__ rank,
                            const float* __restrict__ feature,
                            unsigned short* __restrict__ fb, int E, int NF4,
                            const float* __restrict__ W,
                            unsigned short* __restrict__ wt) {
    int tid = blockIdx.x * blockDim.x + threadIdx.x;
    int stride = gridDim.x * blockDim.x;
    for (int base = tid * 4; base < E; base += stride * 4) {
        if (base + 4 <= E) {
            int4 d4 = *reinterpret_cast<const int4*>(dst + base);
            int4 r4;
            r4.x = atomicAdd(&cnt[d4.x], 1);
            r4.y = atomicAdd(&cnt[d4.y], 1);
            r4.z = atomicAdd(&cnt[d4.z], 1);
            r4.w = atomicAdd(&cnt[d4.w], 1);
            *reinterpret_cast<int4*>(rank + base) = r4;
        } else {
            for (int i = base; i < E; ++i) rank[i] = atomicAdd(&cnt[dst[i]], 1);
        }
    }
    const f32x4* f4 = reinterpret_cast<const f32x4*>(feature);
    ushort4* fb4 = reinterpret_cast<ushort4*>(fb);
    for (int i = tid; i < NF4; i += stride) {
        f32x4 v = f4[i];
        ushort4 o;
        o.x = f2bf(v[0]);
        o.y = f2bf(v[1]);
        o.z = f2bf(v[2]);
        o.w = f2bf(v[3]);
        fb4[i] = o;
    }
    for (int i = tid; i < D * D; i += stride) {
        int n = i >> 7, k = i & 127;
        wt[i] = f2bf(W[k * D + n]);
    }
}

// unordered per-node base allocation (wave-aggregated single counter)
__global__ void k_alloc(const int* __restrict__ cnt, int* __restrict__ offset,
                        int* __restrict__ gtot, int N) {
    int i = blockIdx.x * blockDim.x + threadIdx.x;
    int lane = threadIdx.x & 63;
    int c = (i < N) ? cnt[i] : 0;
    int s = c;
    #pragma unroll
    for (int o = 1; o < 64; o <<= 1) {
        int t = __shfl_up(s, o);
        if (lane >= o) s += t;
    }
    int wavesum = __shfl(s, 63);
    int base = 0;
    if (lane == 0) base = atomicAdd(gtot, wavesum);
    base = __shfl(base, 0);
    if (i < N) offset[i] = base + s - c;
}

// atomic-free fill: pure permutation scatter using precomputed ranks.
__global__ void k_fill_rank(const int* __restrict__ src,
                            const int* __restrict__ dst,
                            const int* __restrict__ rank,
                            const int* __restrict__ offset,
                            unsigned short* __restrict__ srcs, int E) {
    int t = blockIdx.x * blockDim.x + threadIdx.x;
    int base = t * 4;
    if (base >= E) return;
    if (base + 4 <= E) {
        int4 d4 = *reinterpret_cast<const int4*>(dst + base);
        int4 s4 = *reinterpret_cast<const int4*>(src + base);
        int4 r4 = *reinterpret_cast<const int4*>(rank + base);
        int o0 = offset[d4.x];
        int o1 = offset[d4.y];
        int o2 = offset[d4.z];
        int o3 = offset[d4.w];
        srcs[o0 + r4.x] = (unsigned short)s4.x;
        srcs[o1 + r4.y] = (unsigned short)s4.y;
        srcs[o2 + r4.z] = (unsigned short)s4.z;
        srcs[o3 + r4.w] = (unsigned short)s4.w;
    } else {
        for (int i = base; i < E; ++i)
            srcs[offset[dst[i]] + rank[i]] = (unsigned short)src[i];
    }
}

// aggregate from bf16 feature: one wave per node, 4 edges in flight
__global__ __launch_bounds__(256) void k_aggregate_u16(
    const unsigned short* __restrict__ fb,
    const unsigned short* __restrict__ srcs, const int* __restrict__ offset,
    const int* __restrict__ cnt, unsigned short* __restrict__ hb, int N) {
    int w = (blockIdx.x * blockDim.x + threadIdx.x) >> 6;
    int lane = threadIdx.x & 63;
    if (w >= N) return;
    int sub = lane >> 4;
    int l15 = lane & 15;
    int n = cnt[w];
    if (n == 0) {
        if (sub == 0) {
            u16x8 v = *reinterpret_cast<const u16x8*>(fb + (size_t)w * D + l15 * 8);
            *reinterpret_cast<u16x8*>(hb + (size_t)w * D + l15 * 8) = v;
        }
        return;
    }
    int base = offset[w];
    f32x8 acc = {0.f, 0.f, 0.f, 0.f, 0.f, 0.f, 0.f, 0.f};
    int j = 0;
    for (; j + 8 <= n; j += 8) {
        int s0 = srcs[base + j + sub];
        int s1 = srcs[base + j + 4 + sub];
        u16x8 v0 = *reinterpret_cast<const u16x8*>(fb + (size_t)s0 * D + l15 * 8);
        u16x8 v1 = *reinterpret_cast<const u16x8*>(fb + (size_t)s1 * D + l15 * 8);
        #pragma unroll
        for (int q = 0; q < 8; ++q) acc[q] += bf2f((unsigned int)(unsigned short)v0[q]);
        #pragma unroll
        for (int q = 0; q < 8; ++q) acc[q] += bf2f((unsigned int)(unsigned short)v1[q]);
    }
    for (; j < n; j += 4) {
        if (j + sub < n) {
            int s0 = srcs[base + j + sub];
            u16x8 v0 = *reinterpret_cast<const u16x8*>(fb + (size_t)s0 * D + l15 * 8);
            #pragma unroll
            for (int q = 0; q < 8; ++q) acc[q] += bf2f((unsigned int)(unsigned short)v0[q]);
        }
    }
    #pragma unroll
    for (int q = 0; q < 8; ++q) acc[q] += __shfl_xor(acc[q], 16);
    #pragma unroll
    for (int q = 0; q < 8; ++q) acc[q] += __shfl_xor(acc[q], 32);
    if (sub == 0) {
        float r = 1.f / (float)n;
        u16x8 o;
        #pragma unroll
        for (int q = 0; q < 8; ++q) o[q] = f2bf(acc[q] * r);
        *reinterpret_cast<u16x8*>(hb + (size_t)w * D + l15 * 8) = o;
    }
}

// ===========================================================================
// Finalize GEMM: out = relu(h @ W + b). XOR-swizzled LDS, 16x16x32 MFMA.
// ===========================================================================
__global__ __launch_bounds__(256) void k_finalize_mfma(
    const unsigned short* __restrict__ hb, const unsigned short* __restrict__ Wt,
    const float* __restrict__ b, float* __restrict__ out, int N) {
    __shared__ char lds[65536];

    int t = threadIdx.x;
    int row0 = blockIdx.x * 128;

    #pragma unroll
    for (int i = 0; i < 8; ++i) {
        int chunk = i * 256 + t;
        int row = chunk >> 4;
        int c16 = chunk & 15;
        int ldsoff = row * 256 + ((c16 * 16) ^ ((row & 7) << 4));
        f32x4 v = {0.f, 0.f, 0.f, 0.f};
        int grow = row0 + row;
        if (grow < N)
            v = *reinterpret_cast<const f32x4*>(hb + (size_t)grow * D + c16 * 8);
        *reinterpret_cast<f32x4*>(&lds[ldsoff]) = v;
    }
    #pragma unroll
    for (int i = 0; i < 8; ++i) {
        int chunk = i * 256 + t;
        int row = chunk >> 4;
        int c16 = chunk & 15;
        int ldsoff = 32768 + row * 256 + ((c16 * 16) ^ ((row & 7) << 4));
        f32x4 v = *reinterpret_cast<const f32x4*>(Wt + (size_t)row * D + c16 * 8);
        *reinterpret_cast<f32x4*>(&lds[ldsoff]) = v;
    }
    __syncthreads();

    int wv = t >> 6;
    int l = t & 63;
    int l15 = l & 15;
    int lhi = l >> 4;

    f32x4 acc[2][8];
    #pragma unroll
    for (int m = 0; m < 2; ++m)
        #pragma unroll
        for (int n = 0; n < 8; ++n) acc[m][n] = (f32x4){0.f, 0.f, 0.f, 0.f};

    #pragma unroll
    for (int kk = 0; kk < 4; ++kk) {
        int kb = kk * 64 + lhi * 16;
        s16x8 af[2], bf[8];
        #pragma unroll
        for (int m = 0; m < 2; ++m) {
            int r = wv * 32 + m * 16 + l15;
            af[m] = *reinterpret_cast<const s16x8*>(
                &lds[r * 256 + (kb ^ ((r & 7) << 4))]);
        }
        #pragma unroll
        for (int n = 0; n < 8; ++n) {
            int r = n * 16 + l15;
            bf[n] = *reinterpret_cast<const s16x8*>(
                &lds[32768 + r * 256 + (kb ^ ((r & 7) << 4))]);
        }
        #pragma unroll
        for (int m = 0; m < 2; ++m)
            #pragma unroll
            for (int n = 0; n < 8; ++n)
                acc[m][n] = __builtin_amdgcn_mfma_f32_16x16x32_bf16(
                    af[m], bf[n], acc[m][n], 0, 0, 0);
    }

    #pragma unroll
    for (int n = 0; n < 8; ++n) {
        int col = n * 16 + l15;
        float bv = b[col];
        #pragma unroll
        for (int m = 0; m < 2; ++m) {
            int rbase = row0 + wv * 32 + m * 16 + lhi * 4;
            #pragma unroll
            for (int j = 0; j < 4; ++j) {
                int row = rbase + j;
                if (row < N)
                    out[(size_t)row * D + col] = fmaxf(acc[m][n][j] + bv, 0.f);
            }
        }
    }
}

// ===========================================================================
// Tier-B: exact round-4 path (cursor-atomic fill) for smaller workspace
// ===========================================================================
__global__ void k_prep4(const int* __restrict__ dst, int* __restrict__ cnt,
                        const float* __restrict__ feature,
                        unsigned short* __restrict__ fb, int E, int NF4,
                        const float* __restrict__ W,
                        unsigned short* __restrict__ wt) {
    int tid = blockIdx.x * blockDim.x + threadIdx.x;
    int stride = gridDim.x * blockDim.x;
    for (int base = tid * 4; base < E; base += stride * 4) {
        if (base + 4 <= E) {
            int4 d4 = *reinterpret_cast<const int4*>(dst + base);
            atomicAdd(&cnt[d4.x], 1);
            atomicAdd(&cnt[d4.y], 1);
            atomicAdd(&cnt[d4.z], 1);
            atomicAdd(&cnt[d4.w], 1);
        } else {
            for (int i = base; i < E; ++i) atomicAdd(&cnt[dst[i]], 1);
        }
    }
    const f32x4* f4 = reinterpret_cast<const f32x4*>(feature);
    ushort4* fb4 = reinterpret_cast<ushort4*>(fb);
    for (int i = tid; i < NF4; i += stride) {
        f32x4 v = f4[i];
        ushort4 o;
        o.x = f2bf(v[0]);
        o.y = f2bf(v[1]);
        o.z = f2bf(v[2]);
        o.w = f2bf(v[3]);
        fb4[i] = o;
    }
    for (int i = tid; i < D * D; i += stride) {
        int n = i >> 7, k = i & 127;
        wt[i] = f2bf(W[k * D + n]);
    }
}

__global__ void k_alloc2(const int* __restrict__ cnt, int* __restrict__ offset,
                         int* __restrict__ cursor, int* __restrict__ gtot,
                         int N) {
    int i = blockIdx.x * blockDim.x + threadIdx.x;
    int lane = threadIdx.x & 63;
    int c = (i < N) ? cnt[i] : 0;
    int s = c;
    #pragma unroll
    for (int o = 1; o < 64; o <<= 1) {
        int t = __shfl_up(s, o);
        if (lane >= o) s += t;
    }
    int wavesum = __shfl(s, 63);
    int base = 0;
    if (lane == 0) base = atomicAdd(gtot, wavesum);
    base = __shfl(base, 0);
    if (i < N) {
        int off = base + s - c;
        offset[i] = off;
        cursor[i] = off;
    }
}

__global__ void k_fill_u16(const int* __restrict__ src,
                           const int* __restrict__ dst,
                           int* __restrict__ cursor,
                           unsigned short* __restrict__ srcs, int E) {
    int t = blockIdx.x * blockDim.x + threadIdx.x;
    int base = t * 4;
    if (base >= E) return;
    if (base + 4 <= E) {
        int4 d4 = *reinterpret_cast<const int4*>(dst + base);
        int4 s4 = *reinterpret_cast<const int4*>(src + base);
        int p0 = atomicAdd(&cursor[d4.x], 1);
        int p1 = atomicAdd(&cursor[d4.y], 1);
        int p2 = atomicAdd(&cursor[d4.z], 1);
        int p3 = atomicAdd(&cursor[d4.w], 1);
        srcs[p0] = (unsigned short)s4.x;
        srcs[p1] = (unsigned short)s4.y;
        srcs[p2] = (unsigned short)s4.z;
        srcs[p3] = (unsigned short)s4.w;
    } else {
        for (int i = base; i < E; ++i) {
            int p = atomicAdd(&cursor[dst[i]], 1);
            srcs[p] = (unsigned short)src[i];
        }
    }
}

// ===========================================================================
// Tier-C fallback: float-atomic scatter
// ===========================================================================
__global__ void gcn_scatter(const float* __restrict__ feature,
                            const int* __restrict__ src,
                            const int* __restrict__ dst,
                            float* __restrict__ agg,
                            float* __restrict__ deg, int n_edges) {
    int gid = blockIdx.x * blockDim.x + threadIdx.x;
    int e = gid >> 6;
    int lane = gid & 63;
    if (e >= n_edges) return;
    int s = src[e];
    int d = dst[e];
    const float2 v =
        *reinterpret_cast<const float2*>(feature + (size_t)s * D + lane * 2);
    float* o = agg + (size_t)d * D + lane * 2;
    atomicAdd(o, v.x);
    atomicAdd(o + 1, v.y);
    if (lane == 0) atomicAdd(deg + d, 1.0f);
}

__global__ __launch_bounds__(256, 2) void gcn_finalize(
    float* __restrict__ inout, const float* __restrict__ feature,
    const float* __restrict__ W, const float* __restrict__ b,
    const float* __restrict__ deg, int n_nodes) {
    __shared__ float Ws[D * D];
    __shared__ float bs[D];
    __shared__ float hs[4][4][D];

    for (int i = threadIdx.x; i < (D * D) / 4; i += blockDim.x)
        reinterpret_cast<float4*>(Ws)[i] = reinterpret_cast<const float4*>(W)[i];
    if (threadIdx.x < D) bs[threadIdx.x] = b[threadIdx.x];
    __syncthreads();

    int wave = threadIdx.x >> 6;
    int lane = threadIdx.x & 63;
    int gwave = (blockIdx.x * blockDim.x + threadIdx.x) >> 6;
    int nwaves = (gridDim.x * blockDim.x) >> 6;
    int ngroups = (n_nodes + 3) / 4;

    for (int g = gwave; g < ngroups; g += nwaves) {
        int row0 = g * 4;
        #pragma unroll
        for (int r = 0; r < 4; ++r) {
            int row = row0 + r;
            if (row < n_nodes) {
                float2 h2;
                float dg = deg[row];
                if (dg > 0.f) {
                    float2 a = *reinterpret_cast<const float2*>(
                        inout + (size_t)row * D + lane * 2);
                    float rd = 1.f / dg;
                    h2.x = a.x * rd;
                    h2.y = a.y * rd;
                } else {
                    h2 = *reinterpret_cast<const float2*>(
                        feature + (size_t)row * D + lane * 2);
                }
                reinterpret_cast<float2*>(hs[wave][r])[lane] = h2;
            }
        }
        float acc2[4][2];
        #pragma unroll
        for (int r = 0; r < 4; ++r) {
            acc2[r][0] = bs[lane];
            acc2[r][1] = bs[lane + 64];
        }
        #pragma unroll 4
        for (int k = 0; k < D; ++k) {
            float w0 = Ws[k * D + lane];
            float w1 = Ws[k * D + lane + 64];
            #pragma unroll
            for (int r = 0; r < 4; ++r) {
                float hk = hs[wave][r][k];
                acc2[r][0] = fmaf(hk, w0, acc2[r][0]);
                acc2[r][1] = fmaf(hk, w1, acc2[r][1]);
            }
        }
        #pragma unroll
        for (int r = 0; r < 4; ++r) {
            int row = row0 + r;
            if (row < n_nodes) {
                inout[(size_t)row * D + lane] = fmaxf(acc2[r][0], 0.f);
                inout[(size_t)row * D + lane + 64] = fmaxf(acc2[r][1], 0.f);
            }
        }
    }
}

extern "C" void kernel_launch(void* const* d_in, const int* in_sizes, int n_in,
                              void* d_out, int out_size, void* d_ws,
                              size_t ws_size, hipStream_t stream) {
    const float* feature = (const float*)d_in[0];
    const float* W = (const float*)d_in[1];
    const float* b = (const float*)d_in[2];
    const int* src = (const int*)d_in[3];
    const int* dst = (const int*)d_in[4];
    int n_edges = in_sizes[3];
    int n_nodes = in_sizes[0] / D;

    float* out = (float*)d_out;
    int block = 256;
    int nrows_pad = ((n_nodes + 127) / 128) * 128;

    // ---- PRIMARY layout (ints): cnt[N] | gtot[1] | offset[N] | rank[E]
    //      then u16: srcs[E] | fb[N*D] | hb[pad*D] | wt[D*D]
    size_t intsA = (size_t)2 * n_nodes + 1 + n_edges;
    size_t a_srcs_off = (intsA * sizeof(int) + 255) & ~(size_t)255;
    size_t a_fb_off = (a_srcs_off + (size_t)n_edges * 2 + 255) & ~(size_t)255;
    size_t a_hb_off = (a_fb_off + (size_t)n_nodes * D * 2 + 255) & ~(size_t)255;
    size_t a_wt_off = a_hb_off + (size_t)nrows_pad * D * 2;
    size_t need_a = a_wt_off + (size_t)D * D * 2;

    // ---- tier-B layout (round-4): cnt[N] gtot[1] offset[N] cursor[N] |
    //      srcs u16[E] | fb | hb | wt
    size_t intsB = (size_t)3 * n_nodes + 1;
    size_t b_srcs_off = intsB * sizeof(int);
    size_t b_fb_off = (b_srcs_off + (size_t)n_edges * 2 + 255) & ~(size_t)255;
    size_t b_hb_off = (b_fb_off + (size_t)n_nodes * D * 2 + 255) & ~(size_t)255;
    size_t b_wt_off = b_hb_off + (size_t)nrows_pad * D * 2;
    size_t need_b = b_wt_off + (size_t)D * D * 2;

    if (n_nodes < 65536 && ws_size >= need_a) {
        int* cnt = (int*)d_ws;
        int* gtot = cnt + n_nodes;
        int* offset = gtot + 1;
        int* rank = offset + n_nodes;
        unsigned short* srcs = (unsigned short*)((char*)d_ws + a_srcs_off);
        unsigned short* fb = (unsigned short*)((char*)d_ws + a_fb_off);
        unsigned short* hb = (unsigned short*)((char*)d_ws + a_hb_off);
        unsigned short* wt = (unsigned short*)((char*)d_ws + a_wt_off);

        hipMemsetAsync(cnt, 0, (size_t)(n_nodes + 1) * sizeof(int), stream);
        k_prep_rank<<<2048, block, 0, stream>>>(dst, cnt, rank, feature, fb,
                                                n_edges, n_nodes * D / 4, W, wt);
        k_alloc<<<(n_nodes + block - 1) / block, block, 0, stream>>>(
            cnt, offset, gtot, n_nodes);
        k_fill_rank<<<(n_edges / 4 + block) / block, block, 0, stream>>>(
            src, dst, rank, offset, srcs, n_edges);
        k_aggregate_u16<<<((size_t)n_nodes * 64 + block - 1) / block, block, 0,
                          stream>>>(fb, srcs, offset, cnt, hb, n_nodes);
        k_finalize_mfma<<<(n_nodes + 127) / 128, block, 0, stream>>>(
            hb, wt, b, out, n_nodes);
    } else if (n_nodes < 65536 && ws_size >= need_b) {
        int* cnt = (int*)d_ws;
        int* gtot = cnt + n_nodes;
        int* offset = gtot + 1;
        int* cursor = offset + n_nodes;
        unsigned short* srcs = (unsigned short*)((char*)d_ws + b_srcs_off);
        unsigned short* fb = (unsigned short*)((char*)d_ws + b_fb_off);
        unsigned short* hb = (unsigned short*)((char*)d_ws + b_hb_off);
        unsigned short* wt = (unsigned short*)((char*)d_ws + b_wt_off);

        hipMemsetAsync(cnt, 0, (size_t)(n_nodes + 1) * sizeof(int), stream);
        k_prep4<<<2048, block, 0, stream>>>(dst, cnt, feature, fb, n_edges,
                                            n_nodes * D / 4, W, wt);
        k_alloc2<<<(n_nodes + block - 1) / block, block, 0, stream>>>(
            cnt, offset, cursor, gtot, n_nodes);
        k_fill_u16<<<(n_edges / 4 + block) / block, block, 0, stream>>>(
            src, dst, cursor, srcs, n_edges);
        k_aggregate_u16<<<((size_t)n_nodes * 64 + block - 1) / block, block, 0,
                          stream>>>(fb, srcs, offset, cnt, hb, n_nodes);
        k_finalize_mfma<<<(n_nodes + 127) / 128, block, 0, stream>>>(
            hb, wt, b, out, n_nodes);
    } else {
        float* deg = (float*)d_ws;
        hipMemsetAsync(out, 0, (size_t)out_size * sizeof(float), stream);
        hipMemsetAsync(deg, 0, (size_t)n_nodes * sizeof(float), stream);
        long long total_threads = (long long)n_edges * 64;
        int grid = (int)((total_threads + block - 1) / block);
        gcn_scatter<<<grid, block, 0, stream>>>(feature, src, dst, out, deg,
                                                n_edges);
        gcn_finalize<<<512, block, 0, stream>>>(out, feature, W, b, deg,
                                                n_nodes);
    }
}